// Round 2
// baseline (353.593 us; speedup 1.0000x reference)
//
#include <hip/hip_runtime.h>

// YOLOv1-style loss: S=7, B=2, C=20, L=49, n=16384.
// preds row: [ pcls: 980 | pconf: 98 | pbox: 392 ] = 1470 floats (row align 8B)
// labels row: L * [ obj(1) | tcls(20) | tbox(4) ] = 1225 floats (row align 4B)
// Weights: NOOBJ=0.5, OBJ=0.5, CLS=0.5, COORD=2.5
//
// R2 structure: one block per sample; coalesced float4 staging of both full
// rows into LDS (align-down base + residual offset), compute from LDS.
// Rationale: R1's obj-branchy direct loads fetched only 65 MB but at 1 TB/s
// (latency-bound, stride-100B lane pattern). Full coalesced read of 177 MB
// at ~5 TB/s is faster.

#define PRED_ROW 1470
#define LAB_ROW 1225
#define CONF_BASE 980
#define BOX_BASE 1078
#define W_NOOBJ 0.5f
#define W_OBJ 0.5f
#define W_CLS 0.5f
#define W_COORD 2.5f
#define INV_S (1.0f / 7.0f)

__global__ void zero_out_kernel(float* out) { out[0] = 0.0f; }

__global__ __launch_bounds__(256) void yolo_loss_kernel(
    const float* __restrict__ preds, const float* __restrict__ labels,
    float* __restrict__ out, int n) {
  __shared__ float4 lab4[308];   // up to 3-float lead-in + 1225 floats
  __shared__ float4 pred4[368];  // up to 2-float lead-in + 1470 floats

  const int s = blockIdx.x;
  const int tid = threadIdx.x;

  // ---- stage labels row (align-down to 16B) ----
  size_t lrow = (size_t)s * LAB_ROW;
  size_t lstart = lrow & ~(size_t)3;
  int loff = (int)(lrow - lstart);
  int ln4 = (loff + LAB_ROW + 3) >> 2;  // <= 307
  size_t ltotal = (size_t)n * LAB_ROW;
  for (int i = tid; i < ln4; i += 256) {
    size_t g = lstart + 4 * (size_t)i;
    float4 v;
    if (g + 4 <= ltotal) {
      v = *(const float4*)(labels + g);
    } else {  // tail guard (last block only)
      v.x = (g + 0 < ltotal) ? labels[g + 0] : 0.0f;
      v.y = (g + 1 < ltotal) ? labels[g + 1] : 0.0f;
      v.z = (g + 2 < ltotal) ? labels[g + 2] : 0.0f;
      v.w = (g + 3 < ltotal) ? labels[g + 3] : 0.0f;
    }
    lab4[i] = v;
  }

  // ---- stage preds row ----
  size_t prow = (size_t)s * PRED_ROW;
  size_t pstart = prow & ~(size_t)3;
  int poff = (int)(prow - pstart);
  int pn4 = (poff + PRED_ROW + 3) >> 2;  // <= 368
  size_t ptotal = (size_t)n * PRED_ROW;
  for (int i = tid; i < pn4; i += 256) {
    size_t g = pstart + 4 * (size_t)i;
    float4 v;
    if (g + 4 <= ptotal) {
      v = *(const float4*)(preds + g);
    } else {
      v.x = (g + 0 < ptotal) ? preds[g + 0] : 0.0f;
      v.y = (g + 1 < ptotal) ? preds[g + 1] : 0.0f;
      v.z = (g + 2 < ptotal) ? preds[g + 2] : 0.0f;
      v.w = (g + 3 < ptotal) ? preds[g + 3] : 0.0f;
    }
    pred4[i] = v;
  }

  __syncthreads();

  const float* lab = (const float*)lab4 + loff;  // lab[l*25 + k]
  const float* pr = (const float*)pred4 + poff;  // pr[pred-row index]

  float acc = 0.0f;

  // ---- cls term, distributed over all 256 threads ----
  for (int idx = tid; idx < CONF_BASE; idx += 256) {
    int l = idx / 20;
    int c = idx - l * 20;
    if (lab[l * 25] != 0.0f) {
      float d = lab[l * 25 + 1 + c] - pr[idx];
      acc += W_CLS * d * d;
    }
  }

  // ---- per-cell conf + coord terms, threads 0..48 ----
  if (tid < 49) {
    int l = tid;
    float objf = lab[l * 25];
    float c0 = pr[CONF_BASE + 2 * l];
    float c1 = pr[CONF_BASE + 2 * l + 1];
    if (objf != 0.0f) {
      float bx[8];
#pragma unroll
      for (int k = 0; k < 8; ++k) bx[k] = pr[BOX_BASE + 8 * l + k];
      float tx = lab[l * 25 + 21], ty = lab[l * 25 + 22];
      float tw = lab[l * 25 + 23], th = lab[l * 25 + 24];
      float t0 = tx * INV_S, t1 = ty * INV_S, t2 = tw, t3 = th;

      float iou[2], rmse2[2];
#pragma unroll
      for (int b = 0; b < 2; ++b) {
        float o0 = bx[4 * b + 0] * INV_S;
        float o1 = bx[4 * b + 1] * INV_S;
        float o2 = bx[4 * b + 2] * bx[4 * b + 2];
        float o3 = bx[4 * b + 3] * bx[4 * b + 3];
        float left = fmaxf(t0 - 0.5f * t2, o0 - 0.5f * o2);
        float right = fminf(t0 + 0.5f * t2, o0 + 0.5f * o2);
        float top = fmaxf(t1 - 0.5f * t3, o1 - 0.5f * o3);
        float bot = fminf(t1 + 0.5f * t3, o1 + 0.5f * o3);
        float w = right - left;
        float h = bot - top;
        bool invalid = (w < 0.0f) || (h < 0.0f);
        float inter = invalid ? 0.0f : w * h;
        float uni = t2 * t3 + o2 * o3 - inter;
        iou[b] = invalid ? 0.0f : inter / fmaxf(uni, 1e-12f);
        float d0 = t0 - o0, d1 = t1 - o1, d2 = t2 - o2, d3 = t3 - o3;
        rmse2[b] = d0 * d0 + d1 * d1 + d2 * d2 + d3 * d3;  // sqrt monotone
      }

      float max_iou = fmaxf(iou[0], iou[1]);
      // jnp.argmax/argmin: first index wins ties -> strict compare for idx 1
      int best;
      if (max_iou > 0.0f)
        best = (iou[1] > iou[0]) ? 1 : 0;
      else
        best = (rmse2[1] < rmse2[0]) ? 1 : 0;
      float best_iou = iou[best];

      float cb = (best == 0) ? c0 : c1;
      float co = (best == 0) ? c1 : c0;
      float db = best_iou - cb;
      acc += W_OBJ * db * db + W_NOOBJ * co * co;

      float e0 = tx - bx[best * 4 + 0];
      float e1 = ty - bx[best * 4 + 1];
      float e2 = sqrtf(tw) - bx[best * 4 + 2];
      float e3 = sqrtf(th) - bx[best * 4 + 3];
      acc += W_COORD * (e0 * e0 + e1 * e1 + e2 * e2 + e3 * e3);
    } else {
      acc += W_NOOBJ * (c0 * c0 + c1 * c1);
    }
  }

  // ---- reduce: wave(64) shuffle -> LDS -> one atomic per block ----
#pragma unroll
  for (int off = 32; off > 0; off >>= 1) acc += __shfl_down(acc, off);

  __shared__ float wsum[4];
  int wave = tid >> 6;
  int lane = tid & 63;
  if (lane == 0) wsum[wave] = acc;
  __syncthreads();
  if (tid == 0) {
    atomicAdd(out, wsum[0] + wsum[1] + wsum[2] + wsum[3]);
  }
}

extern "C" void kernel_launch(void* const* d_in, const int* in_sizes, int n_in,
                              void* d_out, int out_size, void* d_ws, size_t ws_size,
                              hipStream_t stream) {
  const float* preds = (const float*)d_in[0];
  const float* labels = (const float*)d_in[1];
  float* out = (float*)d_out;
  int n = in_sizes[0] / PRED_ROW;  // 16384

  zero_out_kernel<<<1, 1, 0, stream>>>(out);
  yolo_loss_kernel<<<n, 256, 0, stream>>>(preds, labels, out, n);
}

// Round 3
// 189.076 us; speedup vs baseline: 1.8701x; 1.8701x over previous
//
#include <hip/hip_runtime.h>

// YOLOv1-style loss: S=7, B=2, C=20, L=49, n=16384.
// preds row: [ pcls: 980 | pconf: 98 | pbox: 392 ] = 1470 floats
// labels row: L * [ obj(1) | tcls(20) | tbox(4) ] = 1225 floats
// Weights: NOOBJ=0.5, OBJ=0.5, CLS=0.5, COORD=2.5
//
// R3: R1 per-cell structure, but ATOMIC-FREE reduction.
// Evidence: R1 = 64.7us/3136 atomics = 20.6 ns/atomic; R2 = 222us/16384
// atomics = 13.5 ns/atomic; both with idle HBM (13%/5%) and idle VALU (~9%)
// -> same-address device atomicAdd serialization was the bottleneck both
// times. Blocks now write partials to distinct d_ws slots; a second tiny
// kernel reduces them.

#define L_CELLS 49
#define PRED_ROW 1470
#define LAB_ROW 1225
#define CONF_BASE 980
#define BOX_BASE 1078
#define W_NOOBJ 0.5f
#define W_OBJ 0.5f
#define W_CLS 0.5f
#define W_COORD 2.5f
#define INV_S (1.0f / 7.0f)

__global__ __launch_bounds__(256) void yolo_loss_kernel(
    const float* __restrict__ preds, const float* __restrict__ labels,
    float* __restrict__ ws, int n) {
  int cell = blockIdx.x * blockDim.x + threadIdx.x;
  int total = n * L_CELLS;
  float acc = 0.0f;
  if (cell < total) {
    int sample = cell / L_CELLS;
    int l = cell - sample * L_CELLS;
    const float* rp = preds + (size_t)sample * PRED_ROW;
    const float* labc = labels + (size_t)sample * LAB_ROW + l * 25;

    float objf = labc[0];
    // pconf: index CONF_BASE + 2l within row; row base even, offset even
    // -> 8B aligned -> float2
    const float2 cf = *(const float2*)(rp + CONF_BASE + 2 * l);
    float c0 = cf.x, c1 = cf.y;

    if (objf != 0.0f) {
      // ---- full path (~15% of cells) ----
      const float* boxp = rp + BOX_BASE + 8 * l;  // 8B aligned
      float bx[8];
#pragma unroll
      for (int k = 0; k < 4; ++k) {
        float2 v = *(const float2*)(boxp + 2 * k);
        bx[2 * k] = v.x;
        bx[2 * k + 1] = v.y;
      }

      float tx = labc[21], ty = labc[22], tw = labc[23], th = labc[24];
      float t0 = tx * INV_S, t1 = ty * INV_S, t2 = tw, t3 = th;

      float iou[2], rmse2[2];
#pragma unroll
      for (int b = 0; b < 2; ++b) {
        float o0 = bx[4 * b + 0] * INV_S;
        float o1 = bx[4 * b + 1] * INV_S;
        float o2 = bx[4 * b + 2] * bx[4 * b + 2];
        float o3 = bx[4 * b + 3] * bx[4 * b + 3];
        float left = fmaxf(t0 - 0.5f * t2, o0 - 0.5f * o2);
        float right = fminf(t0 + 0.5f * t2, o0 + 0.5f * o2);
        float top = fmaxf(t1 - 0.5f * t3, o1 - 0.5f * o3);
        float bot = fminf(t1 + 0.5f * t3, o1 + 0.5f * o3);
        float w = right - left;
        float h = bot - top;
        bool invalid = (w < 0.0f) || (h < 0.0f);
        float inter = invalid ? 0.0f : w * h;
        float uni = t2 * t3 + o2 * o3 - inter;
        iou[b] = invalid ? 0.0f : inter / fmaxf(uni, 1e-12f);
        float d0 = t0 - o0, d1 = t1 - o1, d2 = t2 - o2, d3 = t3 - o3;
        rmse2[b] = d0 * d0 + d1 * d1 + d2 * d2 + d3 * d3;  // sqrt monotone
      }

      float max_iou = fmaxf(iou[0], iou[1]);
      // jnp.argmax/argmin: first index wins ties -> strict compare for idx 1
      int best;
      if (max_iou > 0.0f)
        best = (iou[1] > iou[0]) ? 1 : 0;
      else
        best = (rmse2[1] < rmse2[0]) ? 1 : 0;
      float best_iou = iou[best];

      float cb = (best == 0) ? c0 : c1;
      float co = (best == 0) ? c1 : c0;
      float db = best_iou - cb;
      acc += W_OBJ * db * db + W_NOOBJ * co * co;

      // cls
      const float* pcls = rp + l * 20;
      float clsacc = 0.0f;
#pragma unroll
      for (int c = 0; c < 20; ++c) {
        float d = labc[1 + c] - pcls[c];
        clsacc += d * d;
      }
      acc += W_CLS * clsacc;

      // coord: target (tx, ty, sqrt(tw), sqrt(th)) vs best raw box
      float e0 = tx - bx[best * 4 + 0];
      float e1 = ty - bx[best * 4 + 1];
      float e2 = sqrtf(tw) - bx[best * 4 + 2];
      float e3 = sqrtf(th) - bx[best * 4 + 3];
      acc += W_COORD * (e0 * e0 + e1 * e1 + e2 * e2 + e3 * e3);
    } else {
      // ---- no-obj path (~85%): only conf penalty ----
      acc = W_NOOBJ * (c0 * c0 + c1 * c1);
    }
  }

  // wave(64) shuffle reduction -> LDS -> one ws write per block (no atomic)
#pragma unroll
  for (int off = 32; off > 0; off >>= 1) acc += __shfl_down(acc, off);

  __shared__ float wsum[4];  // 256 threads = 4 waves
  int wave = threadIdx.x >> 6;
  int lane = threadIdx.x & 63;
  if (lane == 0) wsum[wave] = acc;
  __syncthreads();
  if (threadIdx.x == 0) {
    ws[blockIdx.x] = wsum[0] + wsum[1] + wsum[2] + wsum[3];
  }
}

__global__ __launch_bounds__(256) void final_reduce_kernel(
    const float* __restrict__ ws, float* __restrict__ out, int m) {
  float acc = 0.0f;
  for (int i = threadIdx.x; i < m; i += 256) acc += ws[i];
#pragma unroll
  for (int off = 32; off > 0; off >>= 1) acc += __shfl_down(acc, off);
  __shared__ float wsum[4];
  int wave = threadIdx.x >> 6;
  int lane = threadIdx.x & 63;
  if (lane == 0) wsum[wave] = acc;
  __syncthreads();
  if (threadIdx.x == 0) out[0] = wsum[0] + wsum[1] + wsum[2] + wsum[3];
}

extern "C" void kernel_launch(void* const* d_in, const int* in_sizes, int n_in,
                              void* d_out, int out_size, void* d_ws, size_t ws_size,
                              hipStream_t stream) {
  const float* preds = (const float*)d_in[0];
  const float* labels = (const float*)d_in[1];
  float* out = (float*)d_out;
  float* ws = (float*)d_ws;
  int n = in_sizes[0] / PRED_ROW;   // 16384
  int total = n * L_CELLS;          // 802816
  int blocks = (total + 255) / 256; // 3136

  yolo_loss_kernel<<<blocks, 256, 0, stream>>>(preds, labels, ws, n);
  final_reduce_kernel<<<1, 256, 0, stream>>>(ws, out, blocks);
}